// Round 15
// baseline (2442.359 us; speedup 1.0000x reference)
//
#include <hip/hip_runtime.h>
#include <hip/hip_bf16.h>
#include <stdint.h>

typedef unsigned long long u64;
typedef unsigned int u32;
typedef unsigned short u16;

#define B_   4
#define C_   64
#define N_   8192
#define M_   2048
#define KNB  16
#define FLT_MAX_ 3.402823466e+38f
#define SMEM_SZ 87312   // 17408(pt)+256(spn)+69632(lists)+16(flag); 1 block/CU
#define GLATE 60        // groups >= GLATE use fine split
// groups 0..59: NSPLIT 8 (16 tiles/block); groups 60..63: NSPLIT 32 (4 tiles)

__device__ __forceinline__ int clampN(int v) {
    return v < 0 ? 0 : (v > N_ - 1 ? N_ - 1 : v);
}

// ---------------- ws layout (bytes) — TOTAL 524288 ----------------
// idx_ws   : u16[B_*M_]       @ 0       (16384 B)
// nbr_ws   : u16[B_*M_*KNB]   @ 16384   (262144 B)
// pnorm_ws : float[B_*N_]     @ 278528  (131072 B)
// wt_ws    : float[448*64]    @ 409600  (114688 B)
// out0 scratch (consumed in-mega before conv overwrites out0):
//   flags[16] + done[256]                       @ 0      (1088 B)
//   part_hi_e u32[7680*8*17]  (early, slot=b*1920+m)     (4.18 MB)
//   part_lo_e u16[7680*8*17]                              (2.09 MB)
//   part_hi_l u32[512*32*17]  (late,  lslot=b*128+m-1920) (1.11 MB)
//   part_lo_l u16[512*32*17]                              (0.56 MB)
//   total 7.94 MB < 8 MB out0.

__device__ __forceinline__ void pin4(float4& v) {
    asm volatile("" : "+v"(v.x), "+v"(v.y), "+v"(v.z), "+v"(v.w));
}

// DPP wave64 max -> returns wave max broadcast (via lane 63 readlane).
__device__ __forceinline__ float wave_fmax_dpp(float v) {
    float t;
    t = __int_as_float(__builtin_amdgcn_update_dpp(0, __float_as_int(v), 0x111, 0xf, 0xf, true)); v = fmaxf(v, t);
    t = __int_as_float(__builtin_amdgcn_update_dpp(0, __float_as_int(v), 0x112, 0xf, 0xf, true)); v = fmaxf(v, t);
    t = __int_as_float(__builtin_amdgcn_update_dpp(0, __float_as_int(v), 0x114, 0xf, 0xf, true)); v = fmaxf(v, t);
    t = __int_as_float(__builtin_amdgcn_update_dpp(0, __float_as_int(v), 0x118, 0xf, 0xf, true)); v = fmaxf(v, t);
    t = __int_as_float(__builtin_amdgcn_update_dpp(0, __float_as_int(v), 0x142, 0xa, 0xf, true)); v = fmaxf(v, t);
    t = __int_as_float(__builtin_amdgcn_update_dpp(0, __float_as_int(v), 0x143, 0xc, 0xf, true)); v = fmaxf(v, t);
    return __int_as_float(__builtin_amdgcn_readlane(__float_as_int(v), 63));
}

// np-exact FPS step (bit-exact 3-mul/2-add form, NO fma contraction).
// fps closed at ~2014us (r12 falsified pk-fp32; r16 falsified clock lever).
#define FPS_STEP(PX, PY, PZ, DD, J)                                          \
    {                                                                        \
        float dx = __fsub_rn((PX), lx);                                      \
        float dy = __fsub_rn((PY), ly);                                      \
        float dz = __fsub_rn((PZ), lz);                                      \
        float d = __fadd_rn(__fadd_rn(__fmul_rn(dx, dx), __fmul_rn(dy, dy)), \
                            __fmul_rn(dz, dz));                              \
        float nd = fminf((DD), d);                                           \
        (DD) = nd;                                                           \
        bool gt = nd > fm;                                                   \
        fm = gt ? nd : fm;                                                   \
        fj = gt ? (J) : fj;                                                  \
        fx = gt ? (PX) : fx;                                                 \
        fy = gt ? (PY) : fy;                                                 \
        fz = gt ? (PZ) : fz;                                                 \
    }

__global__ void init_kernel(u32* __restrict__ scratch) {
    if (threadIdx.x < 272) scratch[threadIdx.x] = 0;   // flags[16]+done[256]
}

// ==== MEGA: fps + pnorm + wtrans + split-knn (var. granularity) + merge =====
// ROUND 27: r14 tail = 208us vs ~90 predicted => hypothesis: per-block knn
// time inflates ~2x under 250-block contention, and late groups inherit it
// at 16-tile granularity. Fix: groups 60..63 use 32 splits x 4 tiles (each
// ~25-50us even contended); groups 0..59 keep 8 x 16 (huge shadow slack).
// Last-arriver merge widths 8/32, both fully unrolled. Falsification probe:
// flat tail => granularity wasn't the cause => structure at floor.
// Roles: 0-3 fps, 4-67 pnorm, 68-123 wtrans, 124..2555 knn.
__global__ __launch_bounds__(512, 2) void mega_kernel(
    const float* __restrict__ xyz, const float* __restrict__ x,
    const float* __restrict__ W0, const float* __restrict__ W1,
    const float* __restrict__ W2, u16* __restrict__ idx_ws,
    float* __restrict__ pnorm_ws, float* __restrict__ wt,
    float* __restrict__ out1, float* __restrict__ out2,
    u16* __restrict__ nbr_ws,
    u32* __restrict__ part_hi_e, u16* __restrict__ part_lo_e,
    u32* __restrict__ part_hi_l, u16* __restrict__ part_lo_l,
    u32* __restrict__ flags, u32* __restrict__ done) {
    const int bid = blockIdx.x;
    const int tid = threadIdx.x;
    __shared__ __align__(16) char SM[SMEM_SZ];

    if (bid < 4) {
        // ---------------- fps (r0 body) + hist + fused gather -------------
        const int b = bid;
        const int lane = tid & 63;
        const int w = tid >> 6;             // 8 waves
        const float* xb = xyz + b * 3 * N_;
        const int n0 = tid * 16;

        float4* red4 = (float4*)SM;          // [2][8] (256 B)
        int*    redi = (int*)(SM + 256);     // [2][8] (64 B)
        u16*    hist = (u16*)(SM + 320);     // [M_] (4096 B)

        float4 px[4], py[4], pz[4], dd[4];
#pragma unroll
        for (int j4 = 0; j4 < 4; ++j4) {
            px[j4] = *(const float4*)(xb + n0 + j4 * 4);
            py[j4] = *(const float4*)(xb + N_ + n0 + j4 * 4);
            pz[j4] = *(const float4*)(xb + 2 * N_ + n0 + j4 * 4);
            pin4(px[j4]); pin4(py[j4]); pin4(pz[j4]);
            dd[j4] = make_float4(FLT_MAX_, FLT_MAX_, FLT_MAX_, FLT_MAX_);
        }

        int cur = 0;
        float lx = xb[0], ly = xb[N_], lz = xb[2 * N_];
        if (tid == 0) { idx_ws[b * M_ + 0] = 0; hist[0] = 0; }

        for (int s = 1; s < M_; ++s) {
            float fm = -1.0f, fx = 0.f, fy = 0.f, fz = 0.f;
            int fj = 0;
#pragma unroll
            for (int j4 = 0; j4 < 4; ++j4) {
                FPS_STEP(px[j4].x, py[j4].x, pz[j4].x, dd[j4].x, j4 * 4 + 0);
                FPS_STEP(px[j4].y, py[j4].y, pz[j4].y, dd[j4].y, j4 * 4 + 1);
                FPS_STEP(px[j4].z, py[j4].z, pz[j4].z, dd[j4].z, j4 * 4 + 2);
                FPS_STEP(px[j4].w, py[j4].w, pz[j4].w, dd[j4].w, j4 * 4 + 3);
            }
            float wm = wave_fmax_dpp(fm);    // wave-uniform
            u64 bal = __ballot(fm == wm);    // >=1 bit set
            int winlane = (int)__ffsll(bal) - 1;
            const int par = s & 1;
            if (lane == winlane) {
                red4[(par << 3) + w] = make_float4(wm, fx, fy, fz);
                redi[(par << 3) + w] = n0 + fj;
            }
            __syncthreads();
            float4 p0 = red4[par << 3];
            float g = p0.x; float nlx = p0.y, nly = p0.z, nlz = p0.w;
            int ncur = redi[par << 3];
#pragma unroll
            for (int ww = 1; ww < 8; ++ww) {
                float4 p = red4[(par << 3) + ww];
                int id = redi[(par << 3) + ww];
                bool gt = p.x > g;           // strict: keeps first wave on ties
                g = gt ? p.x : g;
                nlx = gt ? p.y : nlx; nly = gt ? p.z : nly; nlz = gt ? p.w : nlz;
                ncur = gt ? id : ncur;
            }
            lx = nlx; ly = nly; lz = nlz; cur = ncur;
            if (tid == 0) {
                idx_ws[b * M_ + s] = (u16)cur; hist[s] = (u16)cur;
                if ((s & 63) == 63)   // amortized agent-release
                    __hip_atomic_store(&flags[b], (u32)s, __ATOMIC_RELEASE,
                                       __HIP_MEMORY_SCOPE_AGENT);
            }
            // single barrier per iter: next iter writes red4[par^1]
        }

        __syncthreads();                     // hist complete
        for (int m = tid; m < M_; m += 512) {
            int idx = (int)hist[m];
            out2[b * M_ + m] = (float)idx;
            out1[(b * 3 + 0) * M_ + m] = xb[idx];
            out1[(b * 3 + 1) * M_ + m] = xb[N_ + idx];
            out1[(b * 3 + 2) * M_ + m] = xb[2 * N_ + idx];
        }
        return;
    }

    if (bid < 68) {
        // ---------------- pnorm: blocks 4..67 ----------------
        int gid = (bid - 4) * 512 + tid;     // 0..32767
        int bb = gid >> 13, n = gid & 8191;
        const float* xb = x + bb * C_ * N_ + n;
        float acc = 0.f;
#pragma unroll 16
        for (int c = 0; c < C_; ++c) { float v = xb[c * N_]; acc = fmaf(v, v, acc); }
        pnorm_ws[gid] = acc;
        __syncthreads();                     // own stores drained
        if (tid == 0)
            __hip_atomic_fetch_add(&flags[4], 1u, __ATOMIC_RELEASE,
                                   __HIP_MEMORY_SCOPE_AGENT);
        return;
    }

    if (bid < 124) {
        // ---------------- wtrans: blocks 68..123 ----------------
        int e = (bid - 68) * 512 + tid;      // 0..28671
        if (e < 8192) {
            int i = e >> 6, o = e & 63;
            wt[e] = W0[o * 128 + i];
        } else if (e < 16384) {
            int e2 = e - 8192; int i = e2 >> 6, o = e2 & 63;
            wt[8192 + e2] = W1[o * 128 + i];
        } else {
            int e2 = e - 16384; int i = e2 >> 6, o = e2 & 63;
            wt[16384 + e2] = W2[o * 192 + i];
        }
        return;
    }

    // --- knn: blocks 124..2555; early grp<60: 8 splits x 16 tiles;
    //     late grp>=60: 32 splits x 4 tiles. Group-major (ready order). -----
    {
        const int kid = bid - 124;           // 0..2431
        int grp, b, sp, nspl, tps;
        if (kid < 1920) {                    // early: (grp*4+b)*8+sp
            grp = kid >> 5;
            b   = (kid >> 3) & 3;
            sp  = kid & 7;
            nspl = 8; tps = 16;
        } else {                             // late: ((grp-60)*4+b)*32+sp
            int k2 = kid - 1920;
            grp = GLATE + (k2 >> 7);
            b   = (k2 >> 5) & 3;
            sp  = k2 & 31;
            nspl = 32; tps = 4;
        }
        const int m0 = grp * 32;

        float* pt    = (float*)SM;             // 64*68 floats (17408 B)
        float* spn   = (float*)(SM + 17408);   // 64 floats (256 B)
        u64*   lists = (u64*)(SM + 17664);     // 512*17 u64 (69632 B)
        int*   lastp = (int*)(SM + 87296);     // last-arriver flag

        if (tid == 0) {
            while (__hip_atomic_load(&flags[4], __ATOMIC_ACQUIRE,
                                     __HIP_MEMORY_SCOPE_AGENT) < 64u)
                __builtin_amdgcn_s_sleep(2);
            const u32 need = (u32)(m0 + 31);
            while (__hip_atomic_load(&flags[b], __ATOMIC_ACQUIRE,
                                     __HIP_MEMORY_SCOPE_AGENT) < need)
                __builtin_amdgcn_s_sleep(2);
        }
        __syncthreads();                       // idx/pnorm valid for this block

        const int q = tid & 31, sub = tid >> 5;   // sub 0..15
        const int m = m0 + q;
        const float* xb = x + b * C_ * N_;
        const int self = clampN((int)idx_ws[b * M_ + m]);

        float4 qv[16];
#pragma unroll
        for (int c4 = 0; c4 < 16; ++c4) {
            qv[c4].x = xb[(c4 * 4 + 0) * N_ + self];
            qv[c4].y = xb[(c4 * 4 + 1) * N_ + self];
            qv[c4].z = xb[(c4 * 4 + 2) * N_ + self];
            qv[c4].w = xb[(c4 * 4 + 3) * N_ + self];
        }
        const float qn = pnorm_ws[b * N_ + self];

        u64* L = lists + tid * 17;
#pragma unroll
        for (int j = 0; j < 17; ++j) L[j] = ~0ULL;
        u64 worst = ~0ULL;

        // ------- double-buffered staging: this split's tiles --------------
        const int tF = sp * tps, tL = tF + tps;
        const int cA = tid >> 4, nqA = tid & 15, csA = cA ^ (nqA << 2);
        const int eB = tid + 512;
        const int cB = eB >> 4, nqB = eB & 15, csB = cB ^ (nqB << 2);
        const float* pA = xb + cA * N_ + nqA * 4;
        const float* pB = xb + cB * N_ + nqB * 4;

        float4 s0 = *(const float4*)(pA + tF * 64);
        float4 s1 = *(const float4*)(pB + tF * 64);
        float sv = (tid < 64) ? pnorm_ws[b * N_ + tF * 64 + tid] : 0.f;

        for (int t = tF; t < tL; ++t) {
            __syncthreads();                   // prev compute done; pt free
            pt[(nqA * 4 + 0) * 68 + csA] = s0.x;
            pt[(nqA * 4 + 1) * 68 + csA] = s0.y;
            pt[(nqA * 4 + 2) * 68 + csA] = s0.z;
            pt[(nqA * 4 + 3) * 68 + csA] = s0.w;
            pt[(nqB * 4 + 0) * 68 + csB] = s1.x;
            pt[(nqB * 4 + 1) * 68 + csB] = s1.y;
            pt[(nqB * 4 + 2) * 68 + csB] = s1.z;
            pt[(nqB * 4 + 3) * 68 + csB] = s1.w;
            if (tid < 64) spn[tid] = sv;
            float4 n0 = make_float4(0.f, 0.f, 0.f, 0.f), n1 = n0;
            float nv = 0.f;
            if (t + 1 < tL) {                  // prefetch next tile (regs)
                n0 = *(const float4*)(pA + (t + 1) * 64);
                n1 = *(const float4*)(pB + (t + 1) * 64);
                if (tid < 64) nv = pnorm_ws[b * N_ + (t + 1) * 64 + tid];
            }
            __syncthreads();                   // pt/spn ready
            const int nb0 = t * 64;
#pragma unroll
            for (int pp = 0; pp < 4; ++pp) {
                int nl = sub * 4 + pp;
                const float* pvbase = pt + nl * 68;
                const int rsw = (nl >> 2) << 2;
                float a0 = 0.f, a1 = 0.f, a2 = 0.f, a3 = 0.f;
#pragma unroll
                for (int c4 = 0; c4 < 16; ++c4) {
                    float4 p = *(const float4*)(pvbase + (((c4 << 2) ^ rsw)));
                    a0 = fmaf(qv[c4].x, p.x, a0);
                    a1 = fmaf(qv[c4].y, p.y, a1);
                    a2 = fmaf(qv[c4].z, p.z, a2);
                    a3 = fmaf(qv[c4].w, p.w, a3);
                }
                float dot = (a0 + a1) + (a2 + a3);
                float d = qn + spn[nl] - 2.0f * dot;
                u32 db = __float_as_uint(d);
                db = (db & 0x80000000u) ? ~db : (db | 0x80000000u);
                u64 key = ((u64)db << 32) | (u32)(nb0 + nl);
                if (key < worst) {
                    int j = 16;
                    while (j > 0 && L[j - 1] > key) { L[j] = L[j - 1]; --j; }
                    L[j] = key;
                    worst = L[16];
                }
            }
            s0 = n0; s1 = n1; sv = nv;
        }
        __syncthreads();
        if (tid < 32) {   // merge 16 sublists -> this split's partial top-17
            int pos[16];
#pragma unroll
            for (int s2 = 0; s2 < 16; ++s2) pos[s2] = 0;
            u32 base;
            if (nspl == 8) {
                const u32 slot = (u32)(b * 1920 + m0 + tid);
                base = (slot * 8 + (u32)sp) * 17;
            } else {
                const u32 lslot = (u32)(b * 128 + (m0 - 1920) + tid);
                base = (lslot * 32 + (u32)sp) * 17;
            }
            u32* ph = (nspl == 8) ? part_hi_e : part_hi_l;
            u16* pl = (nspl == 8) ? part_lo_e : part_lo_l;
            for (int r = 0; r < 17; ++r) {
                u64 best = ~0ULL; int bs = 0;
#pragma unroll
                for (int s2 = 0; s2 < 16; ++s2) {
                    u64 k2 = (pos[s2] < 17) ? lists[(tid + 32 * s2) * 17 + pos[s2]] : ~0ULL;
                    if (k2 < best) { best = k2; bs = s2; }
                }
#pragma unroll
                for (int s2 = 0; s2 < 16; ++s2) pos[s2] += (s2 == bs) ? 1 : 0;
                ph[base + r] = (u32)(best >> 32);
                pl[base + r] = (u16)(best & 0xFFFFu);   // idx < 8192
            }
        }
        __syncthreads();                       // partial stores issued
        if (tid == 0) {
            u32 old = __hip_atomic_fetch_add(&done[b * 64 + grp], 1u,
                                             __ATOMIC_ACQ_REL,
                                             __HIP_MEMORY_SCOPE_AGENT);
            *lastp = (old == (u32)(nspl - 1)) ? 1 : 0;
        }
        __syncthreads();                       // lastp visible

        if (*lastp && tid < 32) {
            // -------- last arriver: final merge for this group ------------
            u16* outp = nbr_ws + (b * M_ + m0 + tid) * KNB;
            if (nspl == 8) {
                const u32 slot = (u32)(b * 1920 + m0 + tid);
                const u32* ph = part_hi_e + (u64)slot * 8 * 17;
                const u16* pl = part_lo_e + (u64)slot * 8 * 17;
                int pos[8];
#pragma unroll
                for (int s = 0; s < 8; ++s) pos[s] = 0;
                for (int r = 0; r < 17; ++r) {
                    u64 best = ~0ULL; int bs = 0;
#pragma unroll
                    for (int s = 0; s < 8; ++s) {
                        int p = pos[s];
                        u64 k = (p < 17) ? ((((u64)ph[s * 17 + p]) << 32) | (u64)pl[s * 17 + p])
                                         : ~0ULL;
                        if (k < best) { best = k; bs = s; }
                    }
#pragma unroll
                    for (int s = 0; s < 8; ++s) pos[s] += (s == bs) ? 1 : 0;
                    if (r > 0) outp[r - 1] = (u16)clampN((int)(best & 0xFFFFu));
                }
            } else {
                const u32 lslot = (u32)(b * 128 + (m0 - 1920) + tid);
                const u32* ph = part_hi_l + (u64)lslot * 32 * 17;
                const u16* pl = part_lo_l + (u64)lslot * 32 * 17;
                int pos[32];
#pragma unroll
                for (int s = 0; s < 32; ++s) pos[s] = 0;
                for (int r = 0; r < 17; ++r) {
                    u64 best = ~0ULL; int bs = 0;
#pragma unroll
                    for (int s = 0; s < 32; ++s) {
                        int p = pos[s];
                        u64 k = (p < 17) ? ((((u64)ph[s * 17 + p]) << 32) | (u64)pl[s * 17 + p])
                                         : ~0ULL;
                        if (k < best) { best = k; bs = s; }
                    }
#pragma unroll
                    for (int s = 0; s < 32; ++s) pos[s] += (s == bs) ? 1 : 0;
                    if (r > 0) outp[r - 1] = (u16)clampN((int)(best & 0xFFFFu));
                }
            }
        }
    }
}

// =================== fused edge-conv x3 + k-maxpool (r6 verbatim) ==========
__device__ __forceinline__ void mm_tile(float a[4][4], const float* __restrict__ w,
                                        const float* __restrict__ s, int ni) {
#pragma unroll 8
    for (int i = 0; i < ni; ++i) {
        const float4 w4 = *(const float4*)(w + i * 64);
        const float4 e4 = *(const float4*)(s + i * 64);
        a[0][0] = fmaf(w4.x, e4.x, a[0][0]);
        a[0][1] = fmaf(w4.x, e4.y, a[0][1]);
        a[0][2] = fmaf(w4.x, e4.z, a[0][2]);
        a[0][3] = fmaf(w4.x, e4.w, a[0][3]);
        a[1][0] = fmaf(w4.y, e4.x, a[1][0]);
        a[1][1] = fmaf(w4.y, e4.y, a[1][1]);
        a[1][2] = fmaf(w4.y, e4.z, a[1][2]);
        a[1][3] = fmaf(w4.y, e4.w, a[1][3]);
        a[2][0] = fmaf(w4.z, e4.x, a[2][0]);
        a[2][1] = fmaf(w4.z, e4.y, a[2][1]);
        a[2][2] = fmaf(w4.z, e4.z, a[2][2]);
        a[2][3] = fmaf(w4.z, e4.w, a[2][3]);
        a[3][0] = fmaf(w4.w, e4.x, a[3][0]);
        a[3][1] = fmaf(w4.w, e4.y, a[3][1]);
        a[3][2] = fmaf(w4.w, e4.z, a[3][2]);
        a[3][3] = fmaf(w4.w, e4.w, a[3][3]);
    }
}

__global__ __launch_bounds__(256) void conv_kernel(const float* __restrict__ x,
                                                   const u16* __restrict__ idx_ws,
                                                   const u16* __restrict__ nbr_ws,
                                                   const float* __restrict__ wt,
                                                   const float* __restrict__ bias0,
                                                   const float* __restrict__ bias1,
                                                   const float* __restrict__ bias2,
                                                   float* __restrict__ out0) {
    __shared__ float E[128 * 64];    // rows 0..63 center; 64..127: nd -> h1 -> h2
    __shared__ float H0[64 * 64];

    const int tid = threadIdx.x;
    const int b = blockIdx.x >> 9;
    const int m0 = (blockIdx.x & 511) * 4;
    const float* xb = x + b * C_ * N_;

    {   // stage edge tile
        const int col = tid & 63;
        const int half = tid >> 6;
        const int m = m0 + (col >> 4);
        const int k = col & 15;
        const int selfm = clampN((int)idx_ws[b * M_ + m]);
        const int nbr = clampN((int)nbr_ws[(b * M_ + m) * KNB + k]);
#pragma unroll
        for (int c2 = 0; c2 < 16; ++c2) {
            int c = half * 16 + c2;
            float ctr = xb[c * N_ + selfm];
            float nb = xb[c * N_ + nbr];
            E[c * 64 + col] = ctr;
            E[(64 + c) * 64 + col] = __fsub_rn(nb, ctr);
        }
    }
    __syncthreads();

    const int o0 = (tid >> 4) * 4;
    const int c0 = (tid & 15) * 4;
    float a[4][4];

    {   // conv0 -> H0
        float4 bb = *(const float4*)(bias0 + o0);
        a[0][0] = a[0][1] = a[0][2] = a[0][3] = bb.x;
        a[1][0] = a[1][1] = a[1][2] = a[1][3] = bb.y;
        a[2][0] = a[2][1] = a[2][2] = a[2][3] = bb.z;
        a[3][0] = a[3][1] = a[3][2] = a[3][3] = bb.w;
        mm_tile(a, wt + o0, E + c0, 128);
#pragma unroll
        for (int oo = 0; oo < 4; ++oo) {
            float4 v = make_float4(fmaxf(a[oo][0], 0.f), fmaxf(a[oo][1], 0.f),
                                   fmaxf(a[oo][2], 0.f), fmaxf(a[oo][3], 0.f));
            *(float4*)(H0 + (o0 + oo) * 64 + c0) = v;
        }
    }
    __syncthreads();

    {   // conv1 -> h1 into E rows 64..127 (nd dead after conv0)
        float4 bb = *(const float4*)(bias1 + o0);
        a[0][0] = a[0][1] = a[0][2] = a[0][3] = bb.x;
        a[1][0] = a[1][1] = a[1][2] = a[1][3] = bb.y;
        a[2][0] = a[2][1] = a[2][2] = a[2][3] = bb.z;
        a[3][0] = a[3][1] = a[3][2] = a[3][3] = bb.w;
        mm_tile(a, wt + 8192 + o0, H0 + c0, 64);
        mm_tile(a, wt + 8192 + 64 * 64 + o0, E + c0, 64);
#pragma unroll
        for (int oo = 0; oo < 4; ++oo) {
            float4 v = make_float4(fmaxf(a[oo][0], 0.f), fmaxf(a[oo][1], 0.f),
                                   fmaxf(a[oo][2], 0.f), fmaxf(a[oo][3], 0.f));
            *(float4*)(E + (64 + o0 + oo) * 64 + c0) = v;
        }
    }
    __syncthreads();

    {   // conv2 (no relu), result held in regs until h1 maxpool done
        float4 bb = *(const float4*)(bias2 + o0);
        a[0][0] = a[0][1] = a[0][2] = a[0][3] = bb.x;
        a[1][0] = a[1][1] = a[1][2] = a[1][3] = bb.y;
        a[2][0] = a[2][1] = a[2][2] = a[2][3] = bb.z;
        a[3][0] = a[3][1] = a[3][2] = a[3][3] = bb.w;
        mm_tile(a, wt + 16384 + o0, E + 64 * 64 + c0, 64);
        mm_tile(a, wt + 16384 + 64 * 64 + o0, H0 + c0, 64);
        mm_tile(a, wt + 16384 + 128 * 64 + o0, E + c0, 64);
    }

    // maxpool A: ch 64..255 = [h1, h0, center]
#pragma unroll
    for (int r = 1; r < 4; ++r) {
        int e = tid + r * 256;
        int ch = e >> 2, mloc = e & 3;
        int colb = mloc * 16;
        float v;
        if (ch < 128) {
            const float* row = E + (64 + (ch - 64)) * 64 + colb;
            v = row[0];
#pragma unroll
            for (int k = 1; k < 16; ++k) v = fmaxf(v, row[k]);
        } else if (ch < 192) {
            const float* row = H0 + (ch - 128) * 64 + colb;
            v = row[0];
#pragma unroll
            for (int k = 1; k < 16; ++k) v = fmaxf(v, row[k]);
        } else {
            v = E[(ch - 192) * 64 + colb];
        }
        out0[((b * 256 + ch) << 11) + m0 + mloc] = v;
    }
    __syncthreads();

    {   // write h2 over h1 rows
#pragma unroll
        for (int oo = 0; oo < 4; ++oo) {
            float4 v = make_float4(a[oo][0], a[oo][1], a[oo][2], a[oo][3]);
            *(float4*)(E + (64 + o0 + oo) * 64 + c0) = v;
        }
    }
    __syncthreads();

    {   // maxpool B: ch 0..63 = h2
        int ch = tid >> 2, mloc = tid & 3;
        int colb = mloc * 16;
        const float* row = E + (64 + ch) * 64 + colb;
        float v = row[0];
#pragma unroll
        for (int k = 1; k < 16; ++k) v = fmaxf(v, row[k]);
        out0[((b * 256 + ch) << 11) + m0 + mloc] = v;
    }
}

extern "C" void kernel_launch(void* const* d_in, const int* in_sizes, int n_in,
                              void* d_out, int out_size, void* d_ws, size_t ws_size,
                              hipStream_t stream) {
    const float* x   = (const float*)d_in[0];
    const float* xyz = (const float*)d_in[1];
    const float* W0  = (const float*)d_in[2];
    const float* b0  = (const float*)d_in[3];
    const float* W1  = (const float*)d_in[4];
    const float* b1  = (const float*)d_in[5];
    const float* W2  = (const float*)d_in[6];
    const float* b2  = (const float*)d_in[7];

    float* out  = (float*)d_out;                 // FLOAT32 output buffer
    float* out0 = out;                           // y: 4*256*2048 (8MB)
    float* out1 = out + 4 * 256 * 2048;          // sampled_xyz: 4*3*2048
    float* out2 = out1 + 4 * 3 * 2048;           // sampled_idx (f32): 4*2048
    u32*   scratch   = (u32*)out0;               // overwritten by conv later
    u32*   flags     = scratch;                  // [0..15]
    u32*   done      = scratch + 16;             // [16..271]
    u32*   part_hi_e = scratch + 272;                        // 7680*136 u32
    u16*   part_lo_e = (u16*)(part_hi_e + 7680 * 136);       // 7680*136 u16
    u32*   part_hi_l = (u32*)((char*)part_lo_e + 7680 * 136 * 2);  // 512*544 u32
    u16*   part_lo_l = (u16*)(part_hi_l + 512 * 544);        // 512*544 u16

    char* ws = (char*)d_ws;
    u16*   idx_ws   = (u16*)ws;                  // 16384 B
    u16*   nbr_ws   = (u16*)(ws + 16384);        // 262144 B
    float* pnorm_ws = (float*)(ws + 278528);     // 131072 B
    float* wt_ws    = (float*)(ws + 409600);     // 114688 B

    init_kernel<<<1, 512, 0, stream>>>(scratch);
    mega_kernel<<<2556, 512, 0, stream>>>(xyz, x, W0, W1, W2,
                                          idx_ws, pnorm_ws, wt_ws,
                                          out1, out2, nbr_ws,
                                          part_hi_e, part_lo_e,
                                          part_hi_l, part_lo_l,
                                          flags, done);
    conv_kernel<<<2048, 256, 0, stream>>>(x, idx_ws, nbr_ws, wt_ws,
                                          b0, b1, b2, out0);
}

// Round 16
// 2389.749 us; speedup vs baseline: 1.0220x; 1.0220x over previous
//
#include <hip/hip_runtime.h>
#include <hip/hip_bf16.h>
#include <stdint.h>

typedef unsigned long long u64;
typedef unsigned int u32;
typedef unsigned short u16;

#define B_   4
#define C_   64
#define N_   8192
#define M_   2048
#define KNB  16
#define FLT_MAX_ 3.402823466e+38f
#define SMEM_SZ 87312   // 17408(pt)+256(spn)+69632(lists)+16(flag); 1 block/CU
#define NSPLIT 8        // knn N-scan split (r10/r11/r15 sweep: 8 is optimal)

__device__ __forceinline__ int clampN(int v) {
    return v < 0 ? 0 : (v > N_ - 1 ? N_ - 1 : v);
}

// ---------------- ws layout (bytes) — TOTAL 524288 ----------------
// idx_ws   : u16[B_*M_]       @ 0       (16384 B)
// nbr_ws   : u16[B_*M_*KNB]   @ 16384   (262144 B)
// pnorm_ws : float[B_*N_]     @ 278528  (131072 B)
// wt_ws    : float[448*64]    @ 409600  (114688 B)
// out0 scratch (consumed in-mega before conv overwrites out0):
//   scratch[0..15]   = flags (fps progress[4], pnorm count[4])
//   scratch[16..271] = done[256] per-(b,grp) knn split counters
//   part_hi u32[8192*8*17] @ scratch+272 (4.46MB); part_lo u16[...] after.

__device__ __forceinline__ void pin4(float4& v) {
    asm volatile("" : "+v"(v.x), "+v"(v.y), "+v"(v.z), "+v"(v.w));
}

// DPP wave64 max -> returns wave max broadcast (via lane 63 readlane).
__device__ __forceinline__ float wave_fmax_dpp(float v) {
    float t;
    t = __int_as_float(__builtin_amdgcn_update_dpp(0, __float_as_int(v), 0x111, 0xf, 0xf, true)); v = fmaxf(v, t);
    t = __int_as_float(__builtin_amdgcn_update_dpp(0, __float_as_int(v), 0x112, 0xf, 0xf, true)); v = fmaxf(v, t);
    t = __int_as_float(__builtin_amdgcn_update_dpp(0, __float_as_int(v), 0x114, 0xf, 0xf, true)); v = fmaxf(v, t);
    t = __int_as_float(__builtin_amdgcn_update_dpp(0, __float_as_int(v), 0x118, 0xf, 0xf, true)); v = fmaxf(v, t);
    t = __int_as_float(__builtin_amdgcn_update_dpp(0, __float_as_int(v), 0x142, 0xa, 0xf, true)); v = fmaxf(v, t);
    t = __int_as_float(__builtin_amdgcn_update_dpp(0, __float_as_int(v), 0x143, 0xc, 0xf, true)); v = fmaxf(v, t);
    return __int_as_float(__builtin_amdgcn_readlane(__float_as_int(v), 63));
}

// np-exact FPS step (bit-exact 3-mul/2-add form, NO fma contraction).
// fps closed at ~2014us (r12 falsified pk-fp32; r16 falsified clock lever).
#define FPS_STEP(PX, PY, PZ, DD, J)                                          \
    {                                                                        \
        float dx = __fsub_rn((PX), lx);                                      \
        float dy = __fsub_rn((PY), ly);                                      \
        float dz = __fsub_rn((PZ), lz);                                      \
        float d = __fadd_rn(__fadd_rn(__fmul_rn(dx, dx), __fmul_rn(dy, dy)), \
                            __fmul_rn(dz, dz));                              \
        float nd = fminf((DD), d);                                           \
        (DD) = nd;                                                           \
        bool gt = nd > fm;                                                   \
        fm = gt ? nd : fm;                                                   \
        fj = gt ? (J) : fj;                                                  \
        fx = gt ? (PX) : fx;                                                 \
        fy = gt ? (PY) : fy;                                                 \
        fz = gt ? (PZ) : fz;                                                 \
    }

__global__ void init_kernel(u32* __restrict__ scratch) {
    if (threadIdx.x < 272) scratch[threadIdx.x] = 0;   // flags[16]+done[256]
}

// ==== MEGA: fps + pnorm + wtrans + split-knn with LAST-ARRIVER merge ========
// r14 configuration (best measured: 2392us). r15's fine-split for late
// groups REGRESSED (+50us): tail is scheduler-drain-bound at 1 block/CU,
// not granularity-bound. Roles: 0-3 fps, 4-67 pnorm, 68-123 wtrans,
// 124..2171 knn (grp-major x [b][split]); last split block of each group
// merges partials and writes nbr_ws.
__global__ __launch_bounds__(512, 2) void mega_kernel(
    const float* __restrict__ xyz, const float* __restrict__ x,
    const float* __restrict__ W0, const float* __restrict__ W1,
    const float* __restrict__ W2, u16* __restrict__ idx_ws,
    float* __restrict__ pnorm_ws, float* __restrict__ wt,
    float* __restrict__ out1, float* __restrict__ out2,
    u16* __restrict__ nbr_ws,
    u32* __restrict__ part_hi, u16* __restrict__ part_lo,
    u32* __restrict__ flags, u32* __restrict__ done) {
    const int bid = blockIdx.x;
    const int tid = threadIdx.x;
    __shared__ __align__(16) char SM[SMEM_SZ];

    if (bid < 4) {
        // ---------------- fps (r0 body) + hist + fused gather -------------
        const int b = bid;
        const int lane = tid & 63;
        const int w = tid >> 6;             // 8 waves
        const float* xb = xyz + b * 3 * N_;
        const int n0 = tid * 16;

        float4* red4 = (float4*)SM;          // [2][8] (256 B)
        int*    redi = (int*)(SM + 256);     // [2][8] (64 B)
        u16*    hist = (u16*)(SM + 320);     // [M_] (4096 B)

        float4 px[4], py[4], pz[4], dd[4];
#pragma unroll
        for (int j4 = 0; j4 < 4; ++j4) {
            px[j4] = *(const float4*)(xb + n0 + j4 * 4);
            py[j4] = *(const float4*)(xb + N_ + n0 + j4 * 4);
            pz[j4] = *(const float4*)(xb + 2 * N_ + n0 + j4 * 4);
            pin4(px[j4]); pin4(py[j4]); pin4(pz[j4]);
            dd[j4] = make_float4(FLT_MAX_, FLT_MAX_, FLT_MAX_, FLT_MAX_);
        }

        int cur = 0;
        float lx = xb[0], ly = xb[N_], lz = xb[2 * N_];
        if (tid == 0) { idx_ws[b * M_ + 0] = 0; hist[0] = 0; }

        for (int s = 1; s < M_; ++s) {
            float fm = -1.0f, fx = 0.f, fy = 0.f, fz = 0.f;
            int fj = 0;
#pragma unroll
            for (int j4 = 0; j4 < 4; ++j4) {
                FPS_STEP(px[j4].x, py[j4].x, pz[j4].x, dd[j4].x, j4 * 4 + 0);
                FPS_STEP(px[j4].y, py[j4].y, pz[j4].y, dd[j4].y, j4 * 4 + 1);
                FPS_STEP(px[j4].z, py[j4].z, pz[j4].z, dd[j4].z, j4 * 4 + 2);
                FPS_STEP(px[j4].w, py[j4].w, pz[j4].w, dd[j4].w, j4 * 4 + 3);
            }
            float wm = wave_fmax_dpp(fm);    // wave-uniform
            u64 bal = __ballot(fm == wm);    // >=1 bit set
            int winlane = (int)__ffsll(bal) - 1;
            const int par = s & 1;
            if (lane == winlane) {
                red4[(par << 3) + w] = make_float4(wm, fx, fy, fz);
                redi[(par << 3) + w] = n0 + fj;
            }
            __syncthreads();
            float4 p0 = red4[par << 3];
            float g = p0.x; float nlx = p0.y, nly = p0.z, nlz = p0.w;
            int ncur = redi[par << 3];
#pragma unroll
            for (int ww = 1; ww < 8; ++ww) {
                float4 p = red4[(par << 3) + ww];
                int id = redi[(par << 3) + ww];
                bool gt = p.x > g;           // strict: keeps first wave on ties
                g = gt ? p.x : g;
                nlx = gt ? p.y : nlx; nly = gt ? p.z : nly; nlz = gt ? p.w : nlz;
                ncur = gt ? id : ncur;
            }
            lx = nlx; ly = nly; lz = nlz; cur = ncur;
            if (tid == 0) {
                idx_ws[b * M_ + s] = (u16)cur; hist[s] = (u16)cur;
                if ((s & 63) == 63)   // amortized agent-release
                    __hip_atomic_store(&flags[b], (u32)s, __ATOMIC_RELEASE,
                                       __HIP_MEMORY_SCOPE_AGENT);
            }
            // single barrier per iter: next iter writes red4[par^1]
        }

        __syncthreads();                     // hist complete
        for (int m = tid; m < M_; m += 512) {
            int idx = (int)hist[m];
            out2[b * M_ + m] = (float)idx;
            out1[(b * 3 + 0) * M_ + m] = xb[idx];
            out1[(b * 3 + 1) * M_ + m] = xb[N_ + idx];
            out1[(b * 3 + 2) * M_ + m] = xb[2 * N_ + idx];
        }
        return;
    }

    if (bid < 68) {
        // ---------------- pnorm: blocks 4..67 ----------------
        int gid = (bid - 4) * 512 + tid;     // 0..32767
        int bb = gid >> 13, n = gid & 8191;
        const float* xb = x + bb * C_ * N_ + n;
        float acc = 0.f;
#pragma unroll 16
        for (int c = 0; c < C_; ++c) { float v = xb[c * N_]; acc = fmaf(v, v, acc); }
        pnorm_ws[gid] = acc;
        __syncthreads();                     // own stores drained
        if (tid == 0)
            __hip_atomic_fetch_add(&flags[4], 1u, __ATOMIC_RELEASE,
                                   __HIP_MEMORY_SCOPE_AGENT);
        return;
    }

    if (bid < 124) {
        // ---------------- wtrans: blocks 68..123 ----------------
        int e = (bid - 68) * 512 + tid;      // 0..28671
        if (e < 8192) {
            int i = e >> 6, o = e & 63;
            wt[e] = W0[o * 128 + i];
        } else if (e < 16384) {
            int e2 = e - 8192; int i = e2 >> 6, o = e2 & 63;
            wt[8192 + e2] = W1[o * 128 + i];
        } else {
            int e2 = e - 16384; int i = e2 >> 6, o = e2 & 63;
            wt[16384 + e2] = W2[o * 192 + i];
        }
        return;
    }

    // --- knn: blocks 124..2171, grp-major: kid = ((grp*4)+b)*8 + split -----
    {
        const int kid = bid - 124;           // 0..2047
        const int grp = kid >> 5;            // 0..63 (ready order!)
        const int b   = (kid >> 3) & 3;
        const int sp  = kid & 7;
        const int m0  = grp * 32;

        float* pt    = (float*)SM;             // 64*68 floats (17408 B)
        float* spn   = (float*)(SM + 17408);   // 64 floats (256 B)
        u64*   lists = (u64*)(SM + 17664);     // 512*17 u64 (69632 B)
        int*   lastp = (int*)(SM + 87296);     // last-arriver flag

        if (tid == 0) {
            while (__hip_atomic_load(&flags[4], __ATOMIC_ACQUIRE,
                                     __HIP_MEMORY_SCOPE_AGENT) < 64u)
                __builtin_amdgcn_s_sleep(2);
            const u32 need = (u32)(m0 + 31);
            while (__hip_atomic_load(&flags[b], __ATOMIC_ACQUIRE,
                                     __HIP_MEMORY_SCOPE_AGENT) < need)
                __builtin_amdgcn_s_sleep(2);
        }
        __syncthreads();                       // idx/pnorm valid for this block

        const int q = tid & 31, sub = tid >> 5;   // sub 0..15
        const int m = m0 + q;
        const float* xb = x + b * C_ * N_;
        const int self = clampN((int)idx_ws[b * M_ + m]);

        float4 qv[16];
#pragma unroll
        for (int c4 = 0; c4 < 16; ++c4) {
            qv[c4].x = xb[(c4 * 4 + 0) * N_ + self];
            qv[c4].y = xb[(c4 * 4 + 1) * N_ + self];
            qv[c4].z = xb[(c4 * 4 + 2) * N_ + self];
            qv[c4].w = xb[(c4 * 4 + 3) * N_ + self];
        }
        const float qn = pnorm_ws[b * N_ + self];

        u64* L = lists + tid * 17;
#pragma unroll
        for (int j = 0; j < 17; ++j) L[j] = ~0ULL;
        u64 worst = ~0ULL;

        // ------- double-buffered staging: this split's 16 tiles -----------
        const int tF = sp * 16, tL = tF + 16;
        const int cA = tid >> 4, nqA = tid & 15, csA = cA ^ (nqA << 2);
        const int eB = tid + 512;
        const int cB = eB >> 4, nqB = eB & 15, csB = cB ^ (nqB << 2);
        const float* pA = xb + cA * N_ + nqA * 4;
        const float* pB = xb + cB * N_ + nqB * 4;

        float4 s0 = *(const float4*)(pA + tF * 64);
        float4 s1 = *(const float4*)(pB + tF * 64);
        float sv = (tid < 64) ? pnorm_ws[b * N_ + tF * 64 + tid] : 0.f;

        for (int t = tF; t < tL; ++t) {
            __syncthreads();                   // prev compute done; pt free
            pt[(nqA * 4 + 0) * 68 + csA] = s0.x;
            pt[(nqA * 4 + 1) * 68 + csA] = s0.y;
            pt[(nqA * 4 + 2) * 68 + csA] = s0.z;
            pt[(nqA * 4 + 3) * 68 + csA] = s0.w;
            pt[(nqB * 4 + 0) * 68 + csB] = s1.x;
            pt[(nqB * 4 + 1) * 68 + csB] = s1.y;
            pt[(nqB * 4 + 2) * 68 + csB] = s1.z;
            pt[(nqB * 4 + 3) * 68 + csB] = s1.w;
            if (tid < 64) spn[tid] = sv;
            float4 n0 = make_float4(0.f, 0.f, 0.f, 0.f), n1 = n0;
            float nv = 0.f;
            if (t + 1 < tL) {                  // prefetch next tile (regs)
                n0 = *(const float4*)(pA + (t + 1) * 64);
                n1 = *(const float4*)(pB + (t + 1) * 64);
                if (tid < 64) nv = pnorm_ws[b * N_ + (t + 1) * 64 + tid];
            }
            __syncthreads();                   // pt/spn ready
            const int nb0 = t * 64;
#pragma unroll
            for (int pp = 0; pp < 4; ++pp) {
                int nl = sub * 4 + pp;
                const float* pvbase = pt + nl * 68;
                const int rsw = (nl >> 2) << 2;
                float a0 = 0.f, a1 = 0.f, a2 = 0.f, a3 = 0.f;
#pragma unroll
                for (int c4 = 0; c4 < 16; ++c4) {
                    float4 p = *(const float4*)(pvbase + (((c4 << 2) ^ rsw)));
                    a0 = fmaf(qv[c4].x, p.x, a0);
                    a1 = fmaf(qv[c4].y, p.y, a1);
                    a2 = fmaf(qv[c4].z, p.z, a2);
                    a3 = fmaf(qv[c4].w, p.w, a3);
                }
                float dot = (a0 + a1) + (a2 + a3);
                float d = qn + spn[nl] - 2.0f * dot;
                u32 db = __float_as_uint(d);
                db = (db & 0x80000000u) ? ~db : (db | 0x80000000u);
                u64 key = ((u64)db << 32) | (u32)(nb0 + nl);
                if (key < worst) {
                    int j = 16;
                    while (j > 0 && L[j - 1] > key) { L[j] = L[j - 1]; --j; }
                    L[j] = key;
                    worst = L[16];
                }
            }
            s0 = n0; s1 = n1; sv = nv;
        }
        __syncthreads();
        if (tid < 32) {   // merge 16 sublists -> this split's partial top-17
            int pos[16];
#pragma unroll
            for (int s2 = 0; s2 < 16; ++s2) pos[s2] = 0;
            const u32 base = (u32)(((b * M_ + m0 + tid) * NSPLIT + sp) * 17);
            for (int r = 0; r < 17; ++r) {
                u64 best = ~0ULL; int bs = 0;
#pragma unroll
                for (int s2 = 0; s2 < 16; ++s2) {
                    u64 k2 = (pos[s2] < 17) ? lists[(tid + 32 * s2) * 17 + pos[s2]] : ~0ULL;
                    if (k2 < best) { best = k2; bs = s2; }
                }
#pragma unroll
                for (int s2 = 0; s2 < 16; ++s2) pos[s2] += (s2 == bs) ? 1 : 0;
                part_hi[base + r] = (u32)(best >> 32);
                part_lo[base + r] = (u16)(best & 0xFFFFu);   // idx < 8192
            }
        }
        __syncthreads();                       // partial stores issued
        if (tid == 0) {
            // release our partials; acquire siblings' if we're last
            u32 old = __hip_atomic_fetch_add(&done[b * 64 + grp], 1u,
                                             __ATOMIC_ACQ_REL,
                                             __HIP_MEMORY_SCOPE_AGENT);
            *lastp = (old == (u32)(NSPLIT - 1)) ? 1 : 0;
        }
        __syncthreads();                       // lastp + L1-invalidate visible

        if (*lastp && tid < 32) {
            // -------- last arriver: final 8-way merge for this group ------
            const int gid = b * M_ + m0 + tid;
            const u32* ph = part_hi + (u64)gid * NSPLIT * 17;
            const u16* pl = part_lo + (u64)gid * NSPLIT * 17;
            int pos[NSPLIT];
#pragma unroll
            for (int s = 0; s < NSPLIT; ++s) pos[s] = 0;
            u16* outp = nbr_ws + gid * KNB;
            for (int r = 0; r < 17; ++r) {
                u64 best = ~0ULL; int bs = 0;
#pragma unroll
                for (int s = 0; s < NSPLIT; ++s) {
                    int p = pos[s];
                    u64 k = (p < 17) ? ((((u64)ph[s * 17 + p]) << 32) | (u64)pl[s * 17 + p])
                                     : ~0ULL;
                    if (k < best) { best = k; bs = s; }
                }
#pragma unroll
                for (int s = 0; s < NSPLIT; ++s) pos[s] += (s == bs) ? 1 : 0;
                if (r > 0) outp[r - 1] = (u16)clampN((int)(best & 0xFFFFu));
            }
        }
    }
}

// =================== fused edge-conv x3 + k-maxpool (r6 verbatim) ==========
__device__ __forceinline__ void mm_tile(float a[4][4], const float* __restrict__ w,
                                        const float* __restrict__ s, int ni) {
#pragma unroll 8
    for (int i = 0; i < ni; ++i) {
        const float4 w4 = *(const float4*)(w + i * 64);
        const float4 e4 = *(const float4*)(s + i * 64);
        a[0][0] = fmaf(w4.x, e4.x, a[0][0]);
        a[0][1] = fmaf(w4.x, e4.y, a[0][1]);
        a[0][2] = fmaf(w4.x, e4.z, a[0][2]);
        a[0][3] = fmaf(w4.x, e4.w, a[0][3]);
        a[1][0] = fmaf(w4.y, e4.x, a[1][0]);
        a[1][1] = fmaf(w4.y, e4.y, a[1][1]);
        a[1][2] = fmaf(w4.y, e4.z, a[1][2]);
        a[1][3] = fmaf(w4.y, e4.w, a[1][3]);
        a[2][0] = fmaf(w4.z, e4.x, a[2][0]);
        a[2][1] = fmaf(w4.z, e4.y, a[2][1]);
        a[2][2] = fmaf(w4.z, e4.z, a[2][2]);
        a[2][3] = fmaf(w4.z, e4.w, a[2][3]);
        a[3][0] = fmaf(w4.w, e4.x, a[3][0]);
        a[3][1] = fmaf(w4.w, e4.y, a[3][1]);
        a[3][2] = fmaf(w4.w, e4.z, a[3][2]);
        a[3][3] = fmaf(w4.w, e4.w, a[3][3]);
    }
}

__global__ __launch_bounds__(256) void conv_kernel(const float* __restrict__ x,
                                                   const u16* __restrict__ idx_ws,
                                                   const u16* __restrict__ nbr_ws,
                                                   const float* __restrict__ wt,
                                                   const float* __restrict__ bias0,
                                                   const float* __restrict__ bias1,
                                                   const float* __restrict__ bias2,
                                                   float* __restrict__ out0) {
    __shared__ float E[128 * 64];    // rows 0..63 center; 64..127: nd -> h1 -> h2
    __shared__ float H0[64 * 64];

    const int tid = threadIdx.x;
    const int b = blockIdx.x >> 9;
    const int m0 = (blockIdx.x & 511) * 4;
    const float* xb = x + b * C_ * N_;

    {   // stage edge tile
        const int col = tid & 63;
        const int half = tid >> 6;
        const int m = m0 + (col >> 4);
        const int k = col & 15;
        const int selfm = clampN((int)idx_ws[b * M_ + m]);
        const int nbr = clampN((int)nbr_ws[(b * M_ + m) * KNB + k]);
#pragma unroll
        for (int c2 = 0; c2 < 16; ++c2) {
            int c = half * 16 + c2;
            float ctr = xb[c * N_ + selfm];
            float nb = xb[c * N_ + nbr];
            E[c * 64 + col] = ctr;
            E[(64 + c) * 64 + col] = __fsub_rn(nb, ctr);
        }
    }
    __syncthreads();

    const int o0 = (tid >> 4) * 4;
    const int c0 = (tid & 15) * 4;
    float a[4][4];

    {   // conv0 -> H0
        float4 bb = *(const float4*)(bias0 + o0);
        a[0][0] = a[0][1] = a[0][2] = a[0][3] = bb.x;
        a[1][0] = a[1][1] = a[1][2] = a[1][3] = bb.y;
        a[2][0] = a[2][1] = a[2][2] = a[2][3] = bb.z;
        a[3][0] = a[3][1] = a[3][2] = a[3][3] = bb.w;
        mm_tile(a, wt + o0, E + c0, 128);
#pragma unroll
        for (int oo = 0; oo < 4; ++oo) {
            float4 v = make_float4(fmaxf(a[oo][0], 0.f), fmaxf(a[oo][1], 0.f),
                                   fmaxf(a[oo][2], 0.f), fmaxf(a[oo][3], 0.f));
            *(float4*)(H0 + (o0 + oo) * 64 + c0) = v;
        }
    }
    __syncthreads();

    {   // conv1 -> h1 into E rows 64..127 (nd dead after conv0)
        float4 bb = *(const float4*)(bias1 + o0);
        a[0][0] = a[0][1] = a[0][2] = a[0][3] = bb.x;
        a[1][0] = a[1][1] = a[1][2] = a[1][3] = bb.y;
        a[2][0] = a[2][1] = a[2][2] = a[2][3] = bb.z;
        a[3][0] = a[3][1] = a[3][2] = a[3][3] = bb.w;
        mm_tile(a, wt + 8192 + o0, H0 + c0, 64);
        mm_tile(a, wt + 8192 + 64 * 64 + o0, E + c0, 64);
#pragma unroll
        for (int oo = 0; oo < 4; ++oo) {
            float4 v = make_float4(fmaxf(a[oo][0], 0.f), fmaxf(a[oo][1], 0.f),
                                   fmaxf(a[oo][2], 0.f), fmaxf(a[oo][3], 0.f));
            *(float4*)(E + (64 + o0 + oo) * 64 + c0) = v;
        }
    }
    __syncthreads();

    {   // conv2 (no relu), result held in regs until h1 maxpool done
        float4 bb = *(const float4*)(bias2 + o0);
        a[0][0] = a[0][1] = a[0][2] = a[0][3] = bb.x;
        a[1][0] = a[1][1] = a[1][2] = a[1][3] = bb.y;
        a[2][0] = a[2][1] = a[2][2] = a[2][3] = bb.z;
        a[3][0] = a[3][1] = a[3][2] = a[3][3] = bb.w;
        mm_tile(a, wt + 16384 + o0, E + 64 * 64 + c0, 64);
        mm_tile(a, wt + 16384 + 64 * 64 + o0, H0 + c0, 64);
        mm_tile(a, wt + 16384 + 128 * 64 + o0, E + c0, 64);
    }

    // maxpool A: ch 64..255 = [h1, h0, center]
#pragma unroll
    for (int r = 1; r < 4; ++r) {
        int e = tid + r * 256;
        int ch = e >> 2, mloc = e & 3;
        int colb = mloc * 16;
        float v;
        if (ch < 128) {
            const float* row = E + (64 + (ch - 64)) * 64 + colb;
            v = row[0];
#pragma unroll
            for (int k = 1; k < 16; ++k) v = fmaxf(v, row[k]);
        } else if (ch < 192) {
            const float* row = H0 + (ch - 128) * 64 + colb;
            v = row[0];
#pragma unroll
            for (int k = 1; k < 16; ++k) v = fmaxf(v, row[k]);
        } else {
            v = E[(ch - 192) * 64 + colb];
        }
        out0[((b * 256 + ch) << 11) + m0 + mloc] = v;
    }
    __syncthreads();

    {   // write h2 over h1 rows
#pragma unroll
        for (int oo = 0; oo < 4; ++oo) {
            float4 v = make_float4(a[oo][0], a[oo][1], a[oo][2], a[oo][3]);
            *(float4*)(E + (64 + o0 + oo) * 64 + c0) = v;
        }
    }
    __syncthreads();

    {   // maxpool B: ch 0..63 = h2
        int ch = tid >> 2, mloc = tid & 3;
        int colb = mloc * 16;
        const float* row = E + (64 + ch) * 64 + colb;
        float v = row[0];
#pragma unroll
        for (int k = 1; k < 16; ++k) v = fmaxf(v, row[k]);
        out0[((b * 256 + ch) << 11) + m0 + mloc] = v;
    }
}

extern "C" void kernel_launch(void* const* d_in, const int* in_sizes, int n_in,
                              void* d_out, int out_size, void* d_ws, size_t ws_size,
                              hipStream_t stream) {
    const float* x   = (const float*)d_in[0];
    const float* xyz = (const float*)d_in[1];
    const float* W0  = (const float*)d_in[2];
    const float* b0  = (const float*)d_in[3];
    const float* W1  = (const float*)d_in[4];
    const float* b1  = (const float*)d_in[5];
    const float* W2  = (const float*)d_in[6];
    const float* b2  = (const float*)d_in[7];

    float* out  = (float*)d_out;                 // FLOAT32 output buffer
    float* out0 = out;                           // y: 4*256*2048 (8MB)
    float* out1 = out + 4 * 256 * 2048;          // sampled_xyz: 4*3*2048
    float* out2 = out1 + 4 * 3 * 2048;           // sampled_idx (f32): 4*2048
    u32*   scratch = (u32*)out0;                 // overwritten by conv later
    u32*   flags   = scratch;                    // [0..15]
    u32*   done    = scratch + 16;               // [16..271]
    u32*   part_hi = scratch + 272;              // u32[8192*8*17] (4.46MB)
    u16*   part_lo = (u16*)(part_hi + 8192 * NSPLIT * 17);   // u16[...] (2.23MB)

    char* ws = (char*)d_ws;
    u16*   idx_ws   = (u16*)ws;                  // 16384 B
    u16*   nbr_ws   = (u16*)(ws + 16384);        // 262144 B
    float* pnorm_ws = (float*)(ws + 278528);     // 131072 B
    float* wt_ws    = (float*)(ws + 409600);     // 114688 B

    init_kernel<<<1, 512, 0, stream>>>(scratch);
    mega_kernel<<<2172, 512, 0, stream>>>(xyz, x, W0, W1, W2,
                                          idx_ws, pnorm_ws, wt_ws,
                                          out1, out2, nbr_ws,
                                          part_hi, part_lo, flags, done);
    conv_kernel<<<2048, 256, 0, stream>>>(x, idx_ws, nbr_ws, wt_ws,
                                          b0, b1, b2, out0);
}